// Round 9
// baseline (240.880 us; speedup 1.0000x reference)
//
#include <hip/hip_runtime.h>
#include <stdint.h>

#define NT 4096
#define L2E 1.44269504f

typedef short s16x8 __attribute__((ext_vector_type(8)));
typedef short s16x4 __attribute__((ext_vector_type(4)));
typedef float f32x16 __attribute__((ext_vector_type(16)));
typedef float f32x4 __attribute__((ext_vector_type(4)));

__device__ __forceinline__ unsigned short f2bf(float f) {
  unsigned int u = __float_as_uint(f);
  u = u + 0x7FFFu + ((u >> 16) & 1u);   // RNE to bf16
  return (unsigned short)(u >> 16);
}

// pack 16 f32 p-values into two P fragments (verified R2/R4/R5/R6 map).
__device__ __forceinline__ void pack_pa(const float* p, s16x8* pa) {
  unsigned w8[8];
#pragma unroll
  for (int m = 0; m < 8; ++m)
    asm("v_cvt_pk_bf16_f32 %0, %1, %2" : "=v"(w8[m]) : "v"(p[2 * m]), "v"(p[2 * m + 1]));
  unsigned a0 = w8[0], b0 = w8[2]; asm("v_permlane32_swap_b32 %0, %1" : "+v"(a0), "+v"(b0));
  unsigned a1 = w8[1], b1 = w8[3]; asm("v_permlane32_swap_b32 %0, %1" : "+v"(a1), "+v"(b1));
  unsigned c0 = w8[4], d0 = w8[6]; asm("v_permlane32_swap_b32 %0, %1" : "+v"(c0), "+v"(d0));
  unsigned c1 = w8[5], d1 = w8[7]; asm("v_permlane32_swap_b32 %0, %1" : "+v"(c1), "+v"(d1));
  union PW { unsigned u[4]; s16x8 v; } q0, q1;
  q0.u[0] = a0; q0.u[1] = a1; q0.u[2] = b0; q0.u[3] = b1;
  q1.u[0] = c0; q1.u[1] = c1; q1.u[2] = d0; q1.u[3] = d1;
  pa[0] = q0.v; pa[1] = q1.v;
}

// ============================================================================
// Projection: [wv(128); wq(16); wk(16)*log2e] @ x. grid 256 = b(4) x ntile64.
// Outputs: qws/kws bf16 [b][n][16]; vfrag bf16 [b][jt=n/16][c][hi][8j]
// ============================================================================
__global__ __launch_bounds__(512, 2) void proj_kern(
    const float* __restrict__ x,
    const float* __restrict__ wq, const float* __restrict__ bq,
    const float* __restrict__ wk, const float* __restrict__ bk,
    const float* __restrict__ wv, const float* __restrict__ bv,
    short* __restrict__ qws, short* __restrict__ kws, short* __restrict__ vfrag) {
  __shared__ __align__(16) unsigned short w_s[160 * 128];  // 40960B, swizzled rows (256B)
  __shared__ __align__(16) unsigned short xv_s[128 * 72];  // x tile (stride 64) then V^T scratch (stride 72)

  int t = threadIdx.x;
  int blk = blockIdx.x;
  int b = blk >> 6;
  int n0 = (blk & 63) * 64;

  for (int i4 = t; i4 < 5120; i4 += 512) {
    int row = i4 >> 5, ka = (i4 & 31) * 4;
    f32x4 v;
    float sc = 1.0f;
    if (row < 128)      v = *(const f32x4*)(wv + row * 128 + ka);
    else if (row < 144) v = *(const f32x4*)(wq + (row - 128) * 128 + ka);
    else              { v = *(const f32x4*)(wk + (row - 144) * 128 + ka); sc = L2E; }
    s16x4 o;
#pragma unroll
    for (int j = 0; j < 4; ++j) o[j] = (short)f2bf(v[j] * sc);
    unsigned byt = ((unsigned)(ka * 2)) ^ (((unsigned)row & 7u) << 4);
    *(s16x4*)((char*)w_s + row * 256 + byt) = o;
  }
  {
    int cL = t >> 4, nn4 = (t & 15) * 4;
    for (int cc = 0; cc < 128; cc += 32) {
      int c = cc + cL;
      f32x4 v = *(const f32x4*)(x + ((size_t)b * 128 + c) * NT + n0 + nn4);
      s16x4 o;
#pragma unroll
      for (int j = 0; j < 4; ++j) o[j] = (short)f2bf(v[j]);
      *(s16x4*)(xv_s + c * 64 + nn4) = o;
    }
  }
  __syncthreads();

  int w = t >> 6, lane = t & 63, lc = lane & 31, hi = lane >> 5;
  int rblk = w >> 1, nc = w & 1;
  int nn = nc * 32 + lc;

  f32x16 zf = {0.f,0.f,0.f,0.f,0.f,0.f,0.f,0.f,0.f,0.f,0.f,0.f,0.f,0.f,0.f,0.f};
  f32x16 acc = zf, acc2 = zf;

#pragma unroll
  for (int kk = 0; kk < 8; ++kk) {
    int kb0 = kk * 16 + hi * 8;
    s16x8 xf;
#pragma unroll
    for (int e = 0; e < 8; ++e) xf[e] = (short)xv_s[(kb0 + e) * 64 + nn];
    unsigned byt = ((unsigned)(kk * 32 + hi * 16)) ^ (((unsigned)lc & 7u) << 4);
    s16x8 af = *(const s16x8*)((const char*)w_s + (rblk * 32 + lc) * 256 + byt);
    acc = __builtin_amdgcn_mfma_f32_32x32x16_bf16(af, xf, acc, 0, 0, 0);
    if (rblk == 3) {
      s16x8 af2 = *(const s16x8*)((const char*)w_s + (128 + lc) * 256 + byt);
      acc2 = __builtin_amdgcn_mfma_f32_32x32x16_bf16(af2, xf, acc2, 0, 0, 0);
    }
  }

  if (rblk == 3) {
    size_t nidx = ((size_t)b * NT + n0 + nn) * 16;
    s16x4 q0, q1, k0, k1;
#pragma unroll
    for (int j = 0; j < 4; ++j) {
      q0[j] = (short)f2bf(acc2[j]      + bq[j + 4 * hi]);
      q1[j] = (short)f2bf(acc2[j + 4]  + bq[j + 8 + 4 * hi]);
      k0[j] = (short)f2bf(acc2[j + 8]  + bk[j + 4 * hi] * L2E);
      k1[j] = (short)f2bf(acc2[j + 12] + bk[j + 8 + 4 * hi] * L2E);
    }
    *(s16x4*)(qws + nidx + 4 * hi)     = q0;
    *(s16x4*)(qws + nidx + 8 + 4 * hi) = q1;
    *(s16x4*)(kws + nidx + 4 * hi)     = k0;
    *(s16x4*)(kws + nidx + 8 + 4 * hi) = k1;
  }

  __syncthreads();   // all xv_s (x-tile) reads done
#pragma unroll
  for (int r = 0; r < 16; ++r) {
    int c = rblk * 32 + (r & 3) + 8 * (r >> 2) + 4 * hi;
    xv_s[c * 72 + nn] = f2bf(acc[r] + bv[c]);
  }
  __syncthreads();
#pragma unroll
  for (int p = 0; p < 2; ++p) {
    int gid = t + p * 512;
    int c = gid & 127, ng = gid >> 7;        // ng 0..7 = (jtl<<1)|hi2
    s16x8 v = *(const s16x8*)(xv_s + c * 72 + ng * 8);
    size_t idx = (((size_t)b * 256 + (n0 >> 4) + (ng >> 1)) * 128 + c) * 16 + (ng & 1) * 8;
    *(s16x8*)(vfrag + idx) = v;
  }
}

// ============================================================================
// Flash attention: 1024 thr = 16 waves = 8 private j-streams x 2 c-halves
// (4 waves/SIMD, 1 block/CU). No LDS / no barriers in main loop. Softmax
// phases sequential (e0 then e1, one e-vector live); vB loaded per-sl inside
// PV (latency hidden by TLP). Peak live ~120 VGPR -> fits the 128 cap a
// 1024-thread block requires. Fixed-base softmax p = 2^e. D[i][c].
// ============================================================================
__global__ __launch_bounds__(1024) void attn_mfma(
    const short* __restrict__ qws, const short* __restrict__ kws, const short* __restrict__ vfrag,
    const float* __restrict__ x, const float* __restrict__ gp, float* __restrict__ out) {
  __shared__ __align__(16) unsigned char lds[37120];
  // rg0 @0 (17408B: f32[64][68]), rg1 @17408; lsc @34816 (8*64 f32); linv @36864 (64 f32)

  int g = blockIdx.x;
  int gg = (g & 7) * 32 + (g >> 3);   // XCD swizzle: batch pinned to XCD pair
  int b = gg >> 6;
  int it = gg & 63;
  int t = threadIdx.x;
  int w = t >> 6, lane = t & 63, lc = lane & 31, hi = lane >> 5;
  int s = w >> 1, ch = w & 1;         // j-stream, c-half
  int jt0 = s * 512;

  const short* qb = qws + (size_t)b * NT * 16;
  const short* kb = kws + (size_t)b * NT * 16;
  const short* vfb = vfrag + (size_t)b * 256 * 128 * 16;

  s16x8 qf0 = *(const s16x8*)(qb + (size_t)(it * 64 + lc) * 16 + hi * 8);
  s16x8 qf1 = *(const s16x8*)(qb + (size_t)(it * 64 + 32 + lc) * 16 + hi * 8);

  f32x16 zf = {0.f,0.f,0.f,0.f,0.f,0.f,0.f,0.f,0.f,0.f,0.f,0.f,0.f,0.f,0.f,0.f};
  f32x16 acc[2][2];
  acc[0][0] = zf; acc[0][1] = zf; acc[1][0] = zf; acc[1][1] = zf;
  float lsum0 = 0.f, lsum1 = 0.f;

  s16x8 kf = *(const s16x8*)(kb + (size_t)(jt0 + lc) * 16 + hi * 8);

  for (int st = 0; st < 16; ++st) {
    int jtb = (jt0 >> 4) + st * 2;
    s16x8 kn = kf;
    if (st < 15)
      kn = *(const s16x8*)(kb + (size_t)(jt0 + (st + 1) * 32 + lc) * 16 + hi * 8);

    // ---- phase e0: QK^T (i-sub 0), softmax, pack ----
    s16x8 pa0[2], pa1[2];
    {
      f32x16 e = __builtin_amdgcn_mfma_f32_32x32x16_bf16(kf, qf0, zf, 0, 0, 0);
#pragma unroll
      for (int r = 0; r < 16; ++r) e[r] = __builtin_amdgcn_exp2f(e[r]);
      float a0 = 0.f;
#pragma unroll
      for (int r = 0; r < 16; ++r) a0 += e[r];
      lsum0 += a0;
      pack_pa((const float*)&e, pa0);
    }
    // ---- phase e1: QK^T (i-sub 1), softmax, pack ----
    {
      f32x16 e = __builtin_amdgcn_mfma_f32_32x32x16_bf16(kf, qf1, zf, 0, 0, 0);
#pragma unroll
      for (int r = 0; r < 16; ++r) e[r] = __builtin_amdgcn_exp2f(e[r]);
      float a1 = 0.f;
#pragma unroll
      for (int r = 0; r < 16; ++r) a1 += e[r];
      lsum1 += a1;
      pack_pa((const float*)&e, pa1);
    }

    // ---- PV: per-sl vB loads (8 regs), 4 MFMA each ----
#pragma unroll
    for (int sl = 0; sl < 2; ++sl) {
      s16x8 v0 = *(const s16x8*)(vfb + ((size_t)(jtb + sl) * 128 + (ch * 2 + 0) * 32 + lc) * 16 + hi * 8);
      s16x8 v1 = *(const s16x8*)(vfb + ((size_t)(jtb + sl) * 128 + (ch * 2 + 1) * 32 + lc) * 16 + hi * 8);
      __builtin_amdgcn_s_setprio(1);
      acc[0][0] = __builtin_amdgcn_mfma_f32_32x32x16_bf16(pa0[sl], v0, acc[0][0], 0, 0, 0);
      acc[1][0] = __builtin_amdgcn_mfma_f32_32x32x16_bf16(pa1[sl], v0, acc[1][0], 0, 0, 0);
      acc[0][1] = __builtin_amdgcn_mfma_f32_32x32x16_bf16(pa0[sl], v1, acc[0][1], 0, 0, 0);
      acc[1][1] = __builtin_amdgcn_mfma_f32_32x32x16_bf16(pa1[sl], v1, acc[1][1], 0, 0, 0);
      __builtin_amdgcn_s_setprio(0);
    }
    kf = kn;
  }

  // ---- merge 8 streams per c-half: store (s==0) + LDS atomic adds ----
  float* rgc_my = (float*)(lds + (ch ? 17408 : 0));
  float* lsc  = (float*)(lds + 34816);
  float* linv = (float*)(lds + 36864);

  float lf0 = lsum0 + __shfl_xor(lsum0, 32);
  float lf1 = lsum1 + __shfl_xor(lsum1, 32);
  if (ch == 0 && hi == 0) { lsc[s * 64 + lc] = lf0; lsc[s * 64 + 32 + lc] = lf1; }

  if (s == 0) {
#pragma unroll
    for (int isub = 0; isub < 2; ++isub)
#pragma unroll
      for (int cbi = 0; cbi < 2; ++cbi)
#pragma unroll
        for (int r = 0; r < 16; ++r) {
          int i = isub * 32 + (r & 3) + 8 * (r >> 2) + 4 * hi;
          rgc_my[i * 68 + cbi * 32 + lc] = acc[isub][cbi][r];
        }
  }
  __syncthreads();                                   // B1: lsc + s0 stores done
  if (t < 64) {
    float L = 0.f;
#pragma unroll
    for (int s2 = 0; s2 < 8; ++s2) L += lsc[s2 * 64 + t];
    linv[t] = 1.0f / L;
  }
  if (s != 0) {
#pragma unroll
    for (int isub = 0; isub < 2; ++isub)
#pragma unroll
      for (int cbi = 0; cbi < 2; ++cbi)
#pragma unroll
        for (int r = 0; r < 16; ++r) {
          int i = isub * 32 + (r & 3) + 8 * (r >> 2) + 4 * hi;
          atomicAdd(&rgc_my[i * 68 + cbi * 32 + lc], acc[isub][cbi][r]);
        }
  }
  __syncthreads();                                   // B2: all adds done

  // ---- epilogue: o = gamma * D/L + x ----
  float gam = gp[0];
  int cc = t >> 3, il = (t & 7) * 8;
  const float* rgc = (const float*)(lds + ((cc < 64) ? 0 : 17408));
  int cp = cc & 63;
  size_t base = ((size_t)b * 128 + cc) * NT + it * 64 + il;
#pragma unroll
  for (int q2 = 0; q2 < 2; ++q2) {
    f32x4 xv = *(const f32x4*)(x + base + q2 * 4);
    f32x4 ov;
#pragma unroll
    for (int j = 0; j < 4; ++j) {
      int i = il + q2 * 4 + j;
      ov[j] = gam * rgc[i * 68 + cp] * linv[i] + xv[j];
    }
    *(f32x4*)(out + base + q2 * 4) = ov;
  }
}

extern "C" void kernel_launch(void* const* d_in, const int* in_sizes, int n_in,
                              void* d_out, int out_size, void* d_ws, size_t ws_size,
                              hipStream_t stream) {
  const float* x     = (const float*)d_in[0];
  const float* wq    = (const float*)d_in[1];
  const float* bq    = (const float*)d_in[2];
  const float* wk    = (const float*)d_in[3];
  const float* bk    = (const float*)d_in[4];
  const float* wv    = (const float*)d_in[5];
  const float* bv    = (const float*)d_in[6];
  const float* gamma = (const float*)d_in[7];
  float* out = (float*)d_out;

  short* qws   = (short*)d_ws;                       // 4*4096*16 bf16 = 512 KB
  short* kws   = qws + (size_t)4 * NT * 16;          // 512 KB
  short* vfrag = kws + (size_t)4 * NT * 16;          // 4*256*128*16 bf16 = 4 MB

  proj_kern<<<256, 512, 0, stream>>>(x, wq, bq, wk, bk, wv, bv, qws, kws, vfrag);
  attn_mfma<<<256, 1024, 0, stream>>>(qws, kws, vfrag, x, gamma, out);
}

// Round 11
// 45.051 us; speedup vs baseline: 5.3468x; 5.3468x over previous
//
#include <hip/hip_runtime.h>
#include <stdint.h>

#define NT 4096
#define L2E 1.44269504f

typedef short s16x8 __attribute__((ext_vector_type(8)));
typedef short s16x4 __attribute__((ext_vector_type(4)));
typedef float f32x16 __attribute__((ext_vector_type(16)));
typedef float f32x4 __attribute__((ext_vector_type(4)));

__device__ __forceinline__ unsigned short f2bf(float f) {
  unsigned int u = __float_as_uint(f);
  u = u + 0x7FFFu + ((u >> 16) & 1u);   // RNE to bf16
  return (unsigned short)(u >> 16);
}

// pack 16 f32 p-values into two P A-fragments (verified R2..R6 map)
__device__ __forceinline__ void pack_pa(const float* p, s16x8* pa) {
  unsigned w8[8];
#pragma unroll
  for (int m = 0; m < 8; ++m)
    asm("v_cvt_pk_bf16_f32 %0, %1, %2" : "=v"(w8[m]) : "v"(p[2 * m]), "v"(p[2 * m + 1]));
  unsigned a0 = w8[0], b0 = w8[2]; asm("v_permlane32_swap_b32 %0, %1" : "+v"(a0), "+v"(b0));
  unsigned a1 = w8[1], b1 = w8[3]; asm("v_permlane32_swap_b32 %0, %1" : "+v"(a1), "+v"(b1));
  unsigned c0 = w8[4], d0 = w8[6]; asm("v_permlane32_swap_b32 %0, %1" : "+v"(c0), "+v"(d0));
  unsigned c1 = w8[5], d1 = w8[7]; asm("v_permlane32_swap_b32 %0, %1" : "+v"(c1), "+v"(d1));
  union PW { unsigned u[4]; s16x8 v; } q0, q1;
  q0.u[0] = a0; q0.u[1] = a1; q0.u[2] = b0; q0.u[3] = b1;
  q1.u[0] = c0; q1.u[1] = c1; q1.u[2] = d0; q1.u[3] = d1;
  pa[0] = q0.v; pa[1] = q1.v;
}

// merge helpers; scr layout f32 [32 i][132 c-padded]; i = crow(r,hi), c = cb*32+lc
__device__ __forceinline__ void merge_write(float* scr, const f32x16 (&acc)[4],
                                            int lc, int hi) {
#pragma unroll
  for (int cb = 0; cb < 4; ++cb)
#pragma unroll
    for (int r = 0; r < 16; ++r) {
      int i = (r & 3) + 8 * (r >> 2) + 4 * hi;
      scr[i * 132 + cb * 32 + lc] = acc[cb][r];
    }
}
__device__ __forceinline__ void merge_add(const float* scr, f32x16 (&acc)[4],
                                          int lc, int hi) {
#pragma unroll
  for (int cb = 0; cb < 4; ++cb)
#pragma unroll
    for (int r = 0; r < 16; ++r) {
      int i = (r & 3) + 8 * (r >> 2) + 4 * hi;
      acc[cb][r] += scr[i * 132 + cb * 32 + lc];
    }
}

// ============================================================================
// Projection (R6, verified): [wv(128); wq(16); wk(16)*log2e] @ x.
// grid 256 = b(4) x ntile64. Outputs qws/kws bf16 [b][n][16];
// vfrag bf16 [b][jt=n/16][c][hi][8j]
// ============================================================================
__global__ __launch_bounds__(512, 2) void proj_kern(
    const float* __restrict__ x,
    const float* __restrict__ wq, const float* __restrict__ bq,
    const float* __restrict__ wk, const float* __restrict__ bk,
    const float* __restrict__ wv, const float* __restrict__ bv,
    short* __restrict__ qws, short* __restrict__ kws, short* __restrict__ vfrag) {
  __shared__ __align__(16) unsigned short w_s[160 * 128];  // 40960B, swizzled rows (256B)
  __shared__ __align__(16) unsigned short xv_s[128 * 72];  // x tile (stride 64) then V^T scratch (stride 72)

  int t = threadIdx.x;
  int blk = blockIdx.x;
  int b = blk >> 6;
  int n0 = (blk & 63) * 64;

  for (int i4 = t; i4 < 5120; i4 += 512) {
    int row = i4 >> 5, ka = (i4 & 31) * 4;
    f32x4 v;
    float sc = 1.0f;
    if (row < 128)      v = *(const f32x4*)(wv + row * 128 + ka);
    else if (row < 144) v = *(const f32x4*)(wq + (row - 128) * 128 + ka);
    else              { v = *(const f32x4*)(wk + (row - 144) * 128 + ka); sc = L2E; }
    s16x4 o;
#pragma unroll
    for (int j = 0; j < 4; ++j) o[j] = (short)f2bf(v[j] * sc);
    unsigned byt = ((unsigned)(ka * 2)) ^ (((unsigned)row & 7u) << 4);
    *(s16x4*)((char*)w_s + row * 256 + byt) = o;
  }
  {
    int cL = t >> 4, nn4 = (t & 15) * 4;
    for (int cc = 0; cc < 128; cc += 32) {
      int c = cc + cL;
      f32x4 v = *(const f32x4*)(x + ((size_t)b * 128 + c) * NT + n0 + nn4);
      s16x4 o;
#pragma unroll
      for (int j = 0; j < 4; ++j) o[j] = (short)f2bf(v[j]);
      *(s16x4*)(xv_s + c * 64 + nn4) = o;
    }
  }
  __syncthreads();

  int w = t >> 6, lane = t & 63, lc = lane & 31, hi = lane >> 5;
  int rblk = w >> 1, nc = w & 1;
  int nn = nc * 32 + lc;

  f32x16 zf = {0.f,0.f,0.f,0.f,0.f,0.f,0.f,0.f,0.f,0.f,0.f,0.f,0.f,0.f,0.f,0.f};
  f32x16 acc = zf, acc2 = zf;

#pragma unroll
  for (int kk = 0; kk < 8; ++kk) {
    int kb0 = kk * 16 + hi * 8;
    s16x8 xf;
#pragma unroll
    for (int e = 0; e < 8; ++e) xf[e] = (short)xv_s[(kb0 + e) * 64 + nn];
    unsigned byt = ((unsigned)(kk * 32 + hi * 16)) ^ (((unsigned)lc & 7u) << 4);
    s16x8 af = *(const s16x8*)((const char*)w_s + (rblk * 32 + lc) * 256 + byt);
    acc = __builtin_amdgcn_mfma_f32_32x32x16_bf16(af, xf, acc, 0, 0, 0);
    if (rblk == 3) {
      s16x8 af2 = *(const s16x8*)((const char*)w_s + (128 + lc) * 256 + byt);
      acc2 = __builtin_amdgcn_mfma_f32_32x32x16_bf16(af2, xf, acc2, 0, 0, 0);
    }
  }

  if (rblk == 3) {
    size_t nidx = ((size_t)b * NT + n0 + nn) * 16;
    s16x4 q0, q1, k0, k1;
#pragma unroll
    for (int j = 0; j < 4; ++j) {
      q0[j] = (short)f2bf(acc2[j]      + bq[j + 4 * hi]);
      q1[j] = (short)f2bf(acc2[j + 4]  + bq[j + 8 + 4 * hi]);
      k0[j] = (short)f2bf(acc2[j + 8]  + bk[j + 4 * hi] * L2E);
      k1[j] = (short)f2bf(acc2[j + 12] + bk[j + 8 + 4 * hi] * L2E);
    }
    *(s16x4*)(qws + nidx + 4 * hi)     = q0;
    *(s16x4*)(qws + nidx + 8 + 4 * hi) = q1;
    *(s16x4*)(kws + nidx + 4 * hi)     = k0;
    *(s16x4*)(kws + nidx + 8 + 4 * hi) = k1;
  }

  __syncthreads();   // all xv_s (x-tile) reads done
#pragma unroll
  for (int r = 0; r < 16; ++r) {
    int c = rblk * 32 + (r & 3) + 8 * (r >> 2) + 4 * hi;
    xv_s[c * 72 + nn] = f2bf(acc[r] + bv[c]);
  }
  __syncthreads();
#pragma unroll
  for (int p = 0; p < 2; ++p) {
    int gid = t + p * 512;
    int c = gid & 127, ng = gid >> 7;        // ng 0..7 = (jtl<<1)|hi2
    s16x8 v = *(const s16x8*)(xv_s + c * 72 + ng * 8);
    size_t idx = (((size_t)b * 256 + (n0 >> 4) + (ng >> 1)) * 128 + c) * 16 + (ng & 1) * 8;
    *(s16x8*)(vfrag + idx) = v;
  }
}

// ============================================================================
// Flash attention: grid 512 = b(4) x it(128 tiles of 32 i-rows).
// 256 thr = 4 waves = 4 PRIVATE j-streams (1024 j each). acc[4] = 64 VGPR;
// peak live ~120 -> 4 blocks/CU (16 waves/CU, 4/SIMD). No LDS/barriers in
// main loop. Fixed-base softmax p = 2^e. acc = mfma(P_A, V_B): D[i][c].
// ============================================================================
__global__ __launch_bounds__(256, 4) void attn_mfma(
    const short* __restrict__ qws, const short* __restrict__ kws, const short* __restrict__ vfrag,
    const float* __restrict__ x, const float* __restrict__ gp, float* __restrict__ out) {
  __shared__ __align__(16) unsigned char lds[34432];
  // rg0 @0 (16896B f32[32][132]), rg1 @16896; lsc @33792 (4*32 f32); linv @34304 (32 f32)

  int g = blockIdx.x;
  int gg = (g & 7) * 64 + (g >> 3);   // XCD swizzle: batch pinned to XCD pair
  int b = gg >> 7;
  int it = gg & 127;
  int t = threadIdx.x;
  int w = t >> 6, lane = t & 63, lc = lane & 31, hi = lane >> 5;
  int jt0 = w * 1024;

  const short* qb = qws + (size_t)b * NT * 16;
  const short* kb = kws + (size_t)b * NT * 16;
  const short* vfb = vfrag + (size_t)b * 256 * 128 * 16;

  s16x8 qf = *(const s16x8*)(qb + (size_t)(it * 32 + lc) * 16 + hi * 8);

  f32x16 zf = {0.f,0.f,0.f,0.f,0.f,0.f,0.f,0.f,0.f,0.f,0.f,0.f,0.f,0.f,0.f,0.f};
  f32x16 acc[4];
#pragma unroll
  for (int j = 0; j < 4; ++j) acc[j] = zf;
  float lsum = 0.f;

  for (int st = 0; st < 32; ++st) {
    int j0 = jt0 + st * 32;
    int jtb = j0 >> 4;
    // K fragment + V slice-0 fragments (loads issue together; TLP hides latency)
    s16x8 kf = *(const s16x8*)(kb + (size_t)(j0 + lc) * 16 + hi * 8);
    s16x8 v0[4];
#pragma unroll
    for (int cb = 0; cb < 4; ++cb)
      v0[cb] = *(const s16x8*)(vfb + ((size_t)jtb * 128 + cb * 32 + lc) * 16 + hi * 8);

    // QK^T swapped, exp2 domain: e[r] = E[j0+crow(r,hi)][i0+lc]
    f32x16 e = __builtin_amdgcn_mfma_f32_32x32x16_bf16(kf, qf, zf, 0, 0, 0);
#pragma unroll
    for (int r = 0; r < 16; ++r) e[r] = __builtin_amdgcn_exp2f(e[r]);
    float a0 = 0.f;
#pragma unroll
    for (int r = 0; r < 16; ++r) a0 += e[r];
    lsum += a0;

    s16x8 pa[2];
    pack_pa((const float*)&e, pa);

    // PV slice 0
    __builtin_amdgcn_s_setprio(1);
#pragma unroll
    for (int cb = 0; cb < 4; ++cb)
      acc[cb] = __builtin_amdgcn_mfma_f32_32x32x16_bf16(pa[0], v0[cb], acc[cb], 0, 0, 0);
    __builtin_amdgcn_s_setprio(0);

    // V slice-1 fragments (regs of v0 reusable after slice-0 PV)
    s16x8 v1[4];
#pragma unroll
    for (int cb = 0; cb < 4; ++cb)
      v1[cb] = *(const s16x8*)(vfb + ((size_t)(jtb + 1) * 128 + cb * 32 + lc) * 16 + hi * 8);

    __builtin_amdgcn_s_setprio(1);
#pragma unroll
    for (int cb = 0; cb < 4; ++cb)
      acc[cb] = __builtin_amdgcn_mfma_f32_32x32x16_bf16(pa[1], v1[cb], acc[cb], 0, 0, 0);
    __builtin_amdgcn_s_setprio(0);
  }

  // ---- merge 4 private streams ----
  float* rg0  = (float*)lds;
  float* rg1  = (float*)(lds + 16896);
  float* lsc  = (float*)(lds + 33792);
  float* linv = (float*)(lds + 34304);

  float lf = lsum + __shfl_xor(lsum, 32);   // lanes 0..31 hold L-partial for i = lc
  if (hi == 0) lsc[w * 32 + lc] = lf;
  if (w == 2) merge_write(rg0, acc, lc, hi);
  if (w == 3) merge_write(rg1, acc, lc, hi);
  __syncthreads();                                   // B1
  if (t < 32) {
    float L = lsc[t] + lsc[32 + t] + lsc[64 + t] + lsc[96 + t];
    linv[t] = 1.0f / L;
  }
  if (w == 0) merge_add(rg0, acc, lc, hi);           // {0,2}
  if (w == 1) merge_add(rg1, acc, lc, hi);           // {1,3}
  __syncthreads();                                   // B2
  if (w == 1) merge_write(rg0, acc, lc, hi);
  __syncthreads();                                   // B3
  if (w == 0) {
    merge_add(rg0, acc, lc, hi);                     // all 4 (raw sums)
    merge_write(rg0, acc, lc, hi);
  }
  __syncthreads();                                   // B4

  // ---- epilogue: o = gamma * D/L + x ----
  float gam = gp[0];
  int cc = t >> 1, ih = (t & 1) * 16;
  const float* xb = x + ((size_t)b * 128 + cc) * NT + it * 32 + ih;
  float* ob = out + ((size_t)b * 128 + cc) * NT + it * 32 + ih;
#pragma unroll
  for (int q2 = 0; q2 < 4; ++q2) {
    f32x4 xv = *(const f32x4*)(xb + q2 * 4);
    f32x4 ov;
#pragma unroll
    for (int j = 0; j < 4; ++j) {
      int i = ih + q2 * 4 + j;
      ov[j] = gam * rg0[i * 132 + cc] * linv[i] + xv[j];
    }
    *(f32x4*)(ob + q2 * 4) = ov;
  }
}

extern "C" void kernel_launch(void* const* d_in, const int* in_sizes, int n_in,
                              void* d_out, int out_size, void* d_ws, size_t ws_size,
                              hipStream_t stream) {
  const float* x     = (const float*)d_in[0];
  const float* wq    = (const float*)d_in[1];
  const float* bq    = (const float*)d_in[2];
  const float* wk    = (const float*)d_in[3];
  const float* bk    = (const float*)d_in[4];
  const float* wv    = (const float*)d_in[5];
  const float* bv    = (const float*)d_in[6];
  const float* gamma = (const float*)d_in[7];
  float* out = (float*)d_out;

  short* qws   = (short*)d_ws;                       // 4*4096*16 bf16 = 512 KB
  short* kws   = qws + (size_t)4 * NT * 16;          // 512 KB
  short* vfrag = kws + (size_t)4 * NT * 16;          // 4*256*128*16 bf16 = 4 MB

  proj_kern<<<256, 512, 0, stream>>>(x, wq, bq, wk, bk, wv, bv, qws, kws, vfrag);
  attn_mfma<<<512, 256, 0, stream>>>(qws, kws, vfrag, x, gamma, out);
}